// Round 4
// baseline (238.605 us; speedup 1.0000x reference)
//
#include <hip/hip_runtime.h>
#include <math.h>

#define TOKENS 16384
#define HIDDEN 2048
#define NEXP   64
#define MT     32                  // tokens per block
#define NBLK   (TOKENS / MT)       // 512

#define GATES_OFF (TOKENS * 2)
#define SEL_OFF   (GATES_OFF + TOKENS * NEXP)
#define Z_OFF     (SEL_OFF + TOKENS * 2)

typedef __attribute__((ext_vector_type(8))) _Float16 f16x8;
typedef __attribute__((ext_vector_type(4))) float    f32x4;

// Self-resetting cross-block z-loss accumulator (module globals start at 0;
// the last-arriving block reads+resets, so the invariant holds across graph
// replays -- kernels on one stream are serialized, so no cross-iteration race).
__device__ float    g_zacc = 0.f;
__device__ unsigned g_cnt  = 0u;

__device__ __forceinline__ float wave_sum64(float v) {
    #pragma unroll
    for (int s = 1; s < 64; s <<= 1) v += __shfl_xor(v, s, 64);
    return v;
}

// ---------------------------------------------------------------------------
// fp32 -> (hi, lo*4096) fp16x8 split of 8 floats (two float4).
// hi = RNE fp16 of v; lo = fp16((v - hi) * 4096): identical math to the
// verified wconvert image, now done in-register.
// ---------------------------------------------------------------------------
__device__ __forceinline__ void cvt_split(const float4 a, const float4 b,
                                          f16x8& hi, f16x8& lo) {
    union { _Float16 f[8]; f16x8 v; } H, L;
    #pragma unroll
    for (int j = 0; j < 4; ++j) {
        const float s0 = (&a.x)[j];
        const float s1 = (&b.x)[j];
        const _Float16 h0 = (_Float16)s0;
        const _Float16 h1 = (_Float16)s1;
        H.f[j]     = h0;
        H.f[j + 4] = h1;
        L.f[j]     = (_Float16)((s0 - (float)h0) * 4096.f);
        L.f[j + 4] = (_Float16)((s1 - (float)h1) * 4096.f);
    }
    hi = H.v; lo = L.v;
}

// ---------------------------------------------------------------------------
// One 32-k pipeline stage: raw fp32 A (2 token-rows x 8) + raw fp32 B
// (4 expert-frag rows x 8). All indices compile-time after unroll -> VGPRs.
// ---------------------------------------------------------------------------
struct Stage { float4 a[4]; float4 b[8]; };

__device__ __forceinline__ void load_stage(
    Stage& S, const float* ax0, const float* ax1,
    const float* bw0, const float* bw1, const float* bw2, const float* bw3,
    int s)
{
    const int o = s * 32;
    S.a[0] = *(const float4*)(ax0 + o);
    S.a[1] = *(const float4*)(ax0 + o + 4);
    S.a[2] = *(const float4*)(ax1 + o);
    S.a[3] = *(const float4*)(ax1 + o + 4);
    S.b[0] = *(const float4*)(bw0 + o);
    S.b[1] = *(const float4*)(bw0 + o + 4);
    S.b[2] = *(const float4*)(bw1 + o);
    S.b[3] = *(const float4*)(bw1 + o + 4);
    S.b[4] = *(const float4*)(bw2 + o);
    S.b[5] = *(const float4*)(bw2 + o + 4);
    S.b[6] = *(const float4*)(bw3 + o);
    S.b[7] = *(const float4*)(bw3 + o + 4);
}

__device__ __forceinline__ void consume_stage(
    const Stage& S, f32x4 (&acc0)[2][4], f32x4 (&acc1)[2][4])
{
    f16x8 Ah0, Al0, Ah1, Al1;
    cvt_split(S.a[0], S.a[1], Ah0, Al0);
    cvt_split(S.a[2], S.a[3], Ah1, Al1);
    #pragma unroll
    for (int g = 0; g < 4; ++g) {
        f16x8 bh, bl;
        cvt_split(S.b[2 * g], S.b[2 * g + 1], bh, bl);
        acc0[0][g] = __builtin_amdgcn_mfma_f32_16x16x32_f16(Ah0, bh, acc0[0][g], 0, 0, 0);
        acc0[1][g] = __builtin_amdgcn_mfma_f32_16x16x32_f16(Ah1, bh, acc0[1][g], 0, 0, 0);
        acc1[0][g] = __builtin_amdgcn_mfma_f32_16x16x32_f16(Ah0, bl, acc1[0][g], 0, 0, 0);
        acc1[0][g] = __builtin_amdgcn_mfma_f32_16x16x32_f16(Al0, bh, acc1[0][g], 0, 0, 0);
        acc1[1][g] = __builtin_amdgcn_mfma_f32_16x16x32_f16(Ah1, bl, acc1[1][g], 0, 0, 0);
        acc1[1][g] = __builtin_amdgcn_mfma_f32_16x16x32_f16(Al1, bh, acc1[1][g], 0, 0, 0);
    }
}

// ---------------------------------------------------------------------------
// R7: SINGLE-kernel router. Barrier-free main loop (R3-verified structure):
// 512 blocks x 4 waves; wave wv owns 32 tokens x 64 experts x k in
// [wv*512, wv*512+512), 16 steps of 32k. A and B both load DIRECTLY
// global->VGPR in native 16x16x32 fragment positions:
//   A: lane l = row (l&15) of x, k += (l>>4)*8   [harness-verified R3]
//   B: frag g = expert g*16 + (l&15), k += (l>>4)*8  (the wimg layout
//      collapsed: e = g*16 + (lane&15))           [same math as wconvert]
// fp32 w is converted in-register (hi + lo*4096 fp16 split). 2-stage
// register double-buffer, no __syncthreads in the loop. LDS only for the
// 4-way k-partial logit sum + routing epilogue. z-loss finalized via
// device-scope atomics (no zfinal kernel). Workspace unused.
// ---------------------------------------------------------------------------
__global__ __launch_bounds__(256, 2) void router_full(
    const float* __restrict__ x, const float* __restrict__ w,
    float* __restrict__ out)
{
    __shared__ __align__(16) float lg[4][32 * 66];   // 33792 B k-partial logits
    __shared__ float zred[4];

    const int tid  = threadIdx.x;
    const int wv   = __builtin_amdgcn_readfirstlane(tid >> 6);
    const int lane = tid & 63;
    const int t0   = blockIdx.x * MT;

    const int kbase = wv * 512 + (lane >> 4) * 8;

    // A source: rows t0 + mt*16 + (lane&15)
    const float* ax0 = x + (size_t)(t0 + (lane & 15)) * HIDDEN + kbase;
    const float* ax1 = ax0 + 16 * HIDDEN;

    // B source: frag g reads expert row g*16 + (lane&15), same k pattern
    const float* bw0 = w + (size_t)(lane & 15) * HIDDEN + kbase;
    const float* bw1 = bw0 + 16 * HIDDEN;
    const float* bw2 = bw0 + 32 * HIDDEN;
    const float* bw3 = bw0 + 48 * HIDDEN;

    f32x4 acc0[2][4], acc1[2][4];
    #pragma unroll
    for (int mt = 0; mt < 2; ++mt)
        #pragma unroll
        for (int g = 0; g < 4; ++g) { acc0[mt][g] = (f32x4)0.f; acc1[mt][g] = (f32x4)0.f; }

    Stage SA, SB;

    // prologue: fill both pipeline stages
    load_stage(SA, ax0, ax1, bw0, bw1, bw2, bw3, 0);
    load_stage(SB, ax0, ax1, bw0, bw1, bw2, bw3, 1);

    #pragma unroll
    for (int s = 0; s < 16; s += 2) {
        // even step s: consume SA, refill for s+2
        consume_stage(SA, acc0, acc1);
        if (s + 2 < 16) load_stage(SA, ax0, ax1, bw0, bw1, bw2, bw3, s + 2);
        // odd step s+1: consume SB, refill for s+3
        consume_stage(SB, acc0, acc1);
        if (s + 3 < 16) load_stage(SB, ax0, ax1, bw0, bw1, bw2, bw3, s + 3);
    }

    // ---- epilogue: write this wave's k-partial logits (hi + lo/4096) ----
    #pragma unroll
    for (int mt = 0; mt < 2; ++mt)
        #pragma unroll
        for (int g = 0; g < 4; ++g)
            #pragma unroll
            for (int r = 0; r < 4; ++r) {
                const int tok = mt * 16 + (lane >> 4) * 4 + r;      // C/D row
                const int e   = g * 16 + (lane & 15);               // C/D col
                lg[wv][tok * 66 + e] = acc0[mt][g][r] + acc1[mt][g][r] * (1.f / 4096.f);
            }
    __syncthreads();

    // ---- routing (R1-verified math): wave handles 8 tokens, lane = expert ----
    float zsum = 0.f;
    for (int tt = 0; tt < 8; ++tt) {
        const int t = wv * 8 + tt;
        const int li = t * 66 + lane;
        const float v = lg[0][li] + lg[1][li] + lg[2][li] + lg[3][li];

        float bv = v; int bi = lane;
        #pragma unroll
        for (int s = 1; s < 64; s <<= 1) {
            const float ov = __shfl_xor(bv, s, 64);
            const int   oi = __shfl_xor(bi, s, 64);
            if (ov > bv || (ov == bv && oi < bi)) { bv = ov; bi = oi; }
        }
        const float max1 = bv; const int s1 = bi;

        const float e1 = expf(v - max1);
        const float sume = wave_sum64(e1);
        out[GATES_OFF + (size_t)(t0 + t) * NEXP + lane] = e1 / sume;
        const float lse = max1 + logf(sume);
        zsum += lse * lse;

        const bool mask1 = (max1 - v) > 0.02f * fmaxf(fabsf(v), max1);
        const float sum1 = wave_sum64(mask1 ? 0.f : e1);

        float bv2 = (lane == s1) ? -INFINITY : v; int bi2 = lane;
        #pragma unroll
        for (int s = 1; s < 64; s <<= 1) {
            const float ov = __shfl_xor(bv2, s, 64);
            const int   oi = __shfl_xor(bi2, s, 64);
            if (ov > bv2 || (ov == bv2 && oi < bi2)) { bv2 = ov; bi2 = oi; }
        }
        const float max2 = bv2; const int s2 = bi2;

        const bool mask2 = (max2 - v) > 0.02f * fmaxf(fabsf(v), max2);
        const float p2v = (mask2 || lane == s1) ? 0.f : expf(v - max2);
        const float sum2 = wave_sum64(p2v);

        if (lane == 0) {
            const size_t trow = (size_t)(t0 + t) * 2;
            out[trow + 0] = 1.f / sum1;
            out[trow + 1] = 1.f / sum2;
            out[SEL_OFF + trow + 0] = (float)s1;
            out[SEL_OFF + trow + 1] = (float)s2;
        }
    }

    if (lane == 0) zred[wv] = zsum;
    __syncthreads();

    // ---- z-loss finalize via device-scope atomics (replaces zfinal) ----
    if (tid == 0) {
        const float bz = zred[0] + zred[1] + zred[2] + zred[3];
        atomicAdd(&g_zacc, bz);
        __threadfence();                          // order zacc-add before cnt-add
        const unsigned old = atomicAdd(&g_cnt, 1u);
        if (old == NBLK - 1) {                    // last block: all adds visible
            __threadfence();
            const float tot = atomicExch(&g_zacc, 0.f);   // read total + reset
            atomicExch(&g_cnt, 0u);                       // reset for next replay
            out[Z_OFF] = 0.001f * (tot / (float)TOKENS);
        }
    }
}

extern "C" void kernel_launch(void* const* d_in, const int* in_sizes, int n_in,
                              void* d_out, int out_size, void* d_ws, size_t ws_size,
                              hipStream_t stream) {
    const float* x = (const float*)d_in[0];   // [16384, 2048] fp32
    const float* w = (const float*)d_in[1];   // [64, 2048] fp32
    float* out = (float*)d_out;               // mult(32768) | gates(1048576) | sel(32768) | z(1)
    (void)d_ws; (void)ws_size;                // workspace unused

    router_full<<<NBLK, 256, 0, stream>>>(x, w, out);
}